// Round 2
// 528.686 us; speedup vs baseline: 1.0317x; 1.0317x over previous
//
#include <hip/hip_runtime.h>
#include <math.h>

// Problem constants
constexpr int B_ = 8192;   // batch rows
constexpr int D_ = 1024;   // per-expert dim
constexpr int M_ = 8;      // experts
constexpr int H_ = 256;    // gate hidden

// GEMM1: cat[8192 x 8192] @ W1[8192 x 256], fp32 via bf16-triple MFMA emulation
constexpr int SPLITK = 4;
constexpr int KSP = 2048;          // K per split (16-chunks never straddle expert boundary)
constexpr int BM = 64, BK = 16;    // BM=64 -> grid 128x4 = 512 blocks = 2 blocks/CU
constexpr int NCH = KSP / BK;      // 128 chunks per block
constexpr int NG  = (M_ * D_) / BK; // 512 global 16-k chunks

typedef __bf16 bf16x8 __attribute__((ext_vector_type(8)));
typedef float  f32x16 __attribute__((ext_vector_type(16)));
typedef short  short8 __attribute__((ext_vector_type(8)));
typedef short  short4v __attribute__((ext_vector_type(4)));

__device__ __forceinline__ unsigned short f2bf(float x) {
    unsigned int u = __float_as_uint(x);
    u += 0x7FFFu + ((u >> 16) & 1u);           // round-to-nearest-even
    return (unsigned short)(u >> 16);
}
__device__ __forceinline__ float bf2f(unsigned short s) {
    return __uint_as_float(((unsigned int)s) << 16);
}

#define MFMA(A, Bf, C) __builtin_amdgcn_mfma_f32_32x32x16_bf16((A), (Bf), (C), 0, 0, 0)

#define GLOAD_LDS16(gp, lp)                                                    \
    __builtin_amdgcn_global_load_lds(                                          \
        (const __attribute__((address_space(1))) void*)(gp),                   \
        (__attribute__((address_space(3))) void*)(lp), 16, 0, 0)

// ---------------------------------------------------------------------------
// splitw1: precompute W1's h/m/l bf16 decomposition ONCE, packed in the exact
// per-chunk LDS image layout: P[g][ks][n][8] (g = 16-k chunk, ks = k-half,
// n = column). gemm1 then stages B via pure global_load_lds (no VALU, no
// redundant per-block re-split -- previously done 128x redundantly).
// ---------------------------------------------------------------------------
__global__ __launch_bounds__(256)
void splitw1_kernel(const float* __restrict__ W1, short* __restrict__ Ph,
                    short* __restrict__ Pm, short* __restrict__ Pl)
{
    const int g = blockIdx.x;          // 16-k chunk
    const int t = threadIdx.x;         // column n
    float v[16];
#pragma unroll
    for (int k = 0; k < 16; ++k) v[k] = W1[(size_t)(g * 16 + k) * H_ + t];
#pragma unroll
    for (int ks = 0; ks < 2; ++ks) {
        short8 vh, vm, vl;
#pragma unroll
        for (int j = 0; j < 8; ++j) {
            const float x = v[ks * 8 + j];
            const unsigned short h = f2bf(x);
            float r = x - bf2f(h);
            const unsigned short m = f2bf(r);
            r = r - bf2f(m);
            const unsigned short l = f2bf(r);
            vh[j] = (short)h; vm[j] = (short)m; vl[j] = (short)l;
        }
        const size_t o = ((size_t)(g * 2 + ks) * 256 + t) * 8;
        *(short8*)&Ph[o] = vh;
        *(short8*)&Pm[o] = vm;
        *(short8*)&Pl[o] = vl;
    }
}

// ---------------------------------------------------------------------------
// GEMM1: part[s] = cat[:, sK:(s+1)K] @ W1[sK:(s+1)K, :]
// cat[b,k] = zs[k>>10, b, k&1023].  fp32 emulated as 6 bf16 MFMA passes
// (hh, hm, mh, mm, hl, lh -- bit-identical to previous version).
// BM=64 -> 512 blocks -> 2 blocks/CU; LDS double-buffered (60 KB) -> one
// barrier per chunk; B staged via global_load_lds from precomputed packed W1.
// ---------------------------------------------------------------------------
__global__ __launch_bounds__(256, 2)
void gemm1_kernel(const float* __restrict__ zs,
                  const short* __restrict__ Ph,
                  const short* __restrict__ Pm,
                  const short* __restrict__ Pl,
                  float* __restrict__ part)
{
    // A chunk(ks,m): idx = ks*64 + m, 8 bf16 (k = ks*8..+7) for row m. 2 KB/buf.
    __shared__ short Ah[2][1024], Am_[2][1024], Al[2][1024];
    // B chunk(ks,n): idx = ks*256 + n. 8 KB/buf. Written by global_load_lds
    // (linear lane*16 dest within each wave -- required by HW).
    __shared__ short Bh[2][4096], Bm_[2][4096], Bl[2][4096];

    const int t  = threadIdx.x;
    const int b0 = blockIdx.x * BM;
    const int g0 = blockIdx.y * NCH;   // global chunk base for this split

    // A staging: thread t -> row ar = t>>2 (0..63), k-quarter ap = t&3.
    // Global: lanes 0..3 cover one row's 64 B -> 16x 64B segments per wave.
    const int ar  = t >> 2;
    const int ap  = t & 3;
    const int aof = ((ap >> 1) * 64 + ar) * 8 + (ap & 1) * 4;  // short offset

    const int lane = t & 63;
    const int wv   = t >> 6;        // wave 0..3 -> cols wv*64..+63
    const int kl   = lane >> 5;     // k-half 0/1
    const int ln   = lane & 31;

    f32x16 acc[4];                  // [rt*2 + ctl]
#pragma unroll
    for (int i = 0; i < 4; ++i) acc[i] = (f32x16)0.0f;

    float4 areg;

#define STAGE_B(BUF, G) {                                                      \
    _Pragma("unroll")                                                          \
    for (int ks = 0; ks < 2; ++ks) {                                           \
        const size_t so = (((size_t)(G) * 2 + ks) * 256 + t) * 8;              \
        const int   dof = (ks * 256 + t) * 8;                                  \
        GLOAD_LDS16(Ph + so, &Bh[BUF][dof]);                                   \
        GLOAD_LDS16(Pm + so, &Bm_[BUF][dof]);                                  \
        GLOAD_LDS16(Pl + so, &Bl[BUF][dof]);                                   \
    }                                                                          \
}

#define LOAD_A(G) {                                                            \
    const int kg = (G) * 16;                                                   \
    areg = *(const float4*)(zs + ((size_t)(kg >> 10) * B_ + b0 + ar) * D_      \
                               + (kg & 1023) + ap * 4);                        \
}

#define STORE_A(BUF) {                                                         \
    const float av[4] = {areg.x, areg.y, areg.z, areg.w};                      \
    short4v vh, vm, vl;                                                        \
    _Pragma("unroll")                                                          \
    for (int j = 0; j < 4; ++j) {                                              \
        const unsigned short h = f2bf(av[j]);                                  \
        float r = av[j] - bf2f(h);                                             \
        const unsigned short m = f2bf(r);                                      \
        r = r - bf2f(m);                                                       \
        const unsigned short l = f2bf(r);                                      \
        vh[j] = (short)h; vm[j] = (short)m; vl[j] = (short)l;                  \
    }                                                                          \
    *(short4v*)&Ah[BUF][aof]  = vh;                                            \
    *(short4v*)&Am_[BUF][aof] = vm;                                            \
    *(short4v*)&Al[BUF][aof]  = vl;                                            \
}

    STAGE_B(0, g0)
    LOAD_A(g0)
    STORE_A(0)
    __syncthreads();

    int buf = 0;
#pragma unroll 1
    for (int c = 0; c < NCH; ++c) {
        // Prefetch chunk c+1: async B -> LDS buf^1, A -> registers.
        if (c + 1 < NCH) {
            STAGE_B(buf ^ 1, g0 + c + 1)
            LOAD_A(g0 + c + 1)
        }
        {
            const int ib = (kl * 256 + wv * 64 + ln) * 8;
            const bf16x8 bh0 = __builtin_bit_cast(bf16x8, *(const short8*)&Bh[buf][ib]);
            const bf16x8 bm0 = __builtin_bit_cast(bf16x8, *(const short8*)&Bm_[buf][ib]);
            const bf16x8 bl0 = __builtin_bit_cast(bf16x8, *(const short8*)&Bl[buf][ib]);
            const bf16x8 bh1 = __builtin_bit_cast(bf16x8, *(const short8*)&Bh[buf][ib + 256]);
            const bf16x8 bm1 = __builtin_bit_cast(bf16x8, *(const short8*)&Bm_[buf][ib + 256]);
            const bf16x8 bl1 = __builtin_bit_cast(bf16x8, *(const short8*)&Bl[buf][ib + 256]);
            const int ia = (kl * 64 + ln) * 8;
            const bf16x8 ah0 = __builtin_bit_cast(bf16x8, *(const short8*)&Ah[buf][ia]);
            const bf16x8 am0 = __builtin_bit_cast(bf16x8, *(const short8*)&Am_[buf][ia]);
            const bf16x8 al0 = __builtin_bit_cast(bf16x8, *(const short8*)&Al[buf][ia]);
            const bf16x8 ah1 = __builtin_bit_cast(bf16x8, *(const short8*)&Ah[buf][ia + 256]);
            const bf16x8 am1 = __builtin_bit_cast(bf16x8, *(const short8*)&Am_[buf][ia + 256]);
            const bf16x8 al1 = __builtin_bit_cast(bf16x8, *(const short8*)&Al[buf][ia + 256]);
            // Per-acc order preserved: hh, hm, mh, mm, hl, lh.
            // Interleaved across 4 independent accumulators for MFMA ILP.
            acc[0] = MFMA(ah0, bh0, acc[0]); acc[1] = MFMA(ah0, bh1, acc[1]);
            acc[2] = MFMA(ah1, bh0, acc[2]); acc[3] = MFMA(ah1, bh1, acc[3]);
            acc[0] = MFMA(ah0, bm0, acc[0]); acc[1] = MFMA(ah0, bm1, acc[1]);
            acc[2] = MFMA(ah1, bm0, acc[2]); acc[3] = MFMA(ah1, bm1, acc[3]);
            acc[0] = MFMA(am0, bh0, acc[0]); acc[1] = MFMA(am0, bh1, acc[1]);
            acc[2] = MFMA(am1, bh0, acc[2]); acc[3] = MFMA(am1, bh1, acc[3]);
            acc[0] = MFMA(am0, bm0, acc[0]); acc[1] = MFMA(am0, bm1, acc[1]);
            acc[2] = MFMA(am1, bm0, acc[2]); acc[3] = MFMA(am1, bm1, acc[3]);
            acc[0] = MFMA(ah0, bl0, acc[0]); acc[1] = MFMA(ah0, bl1, acc[1]);
            acc[2] = MFMA(ah1, bl0, acc[2]); acc[3] = MFMA(ah1, bl1, acc[3]);
            acc[0] = MFMA(al0, bh0, acc[0]); acc[1] = MFMA(al0, bh1, acc[1]);
            acc[2] = MFMA(al1, bh0, acc[2]); acc[3] = MFMA(al1, bh1, acc[3]);
        }
        // Split+store A(c+1) into buf^1 (disjoint from compute buf -> no
        // barrier needed between; compiler can interleave VALU with MFMA).
        if (c + 1 < NCH) STORE_A(buf ^ 1)
        __syncthreads();   // drains vmcnt (B gloads) + lgkm (A writes)
        buf ^= 1;
    }
#undef STAGE_B
#undef LOAD_A
#undef STORE_A

    // Epilogue: C/D layout (verified m74/m101): col = ln, row = (r&3)+8*(r>>2)+4*kl
    float* P = part + ((size_t)blockIdx.y * B_ + b0) * H_;
#pragma unroll
    for (int rt = 0; rt < 2; ++rt) {
#pragma unroll
        for (int ctl = 0; ctl < 2; ++ctl) {
            const f32x16 v = acc[rt * 2 + ctl];
            const int col = wv * 64 + ctl * 32 + ln;
#pragma unroll
            for (int r = 0; r < 16; ++r) {
                const int row = rt * 32 + (r & 3) + 8 * (r >> 2) + 4 * kl;
                P[(size_t)row * H_ + col] = v[r];
            }
        }
    }
}

// ---------------------------------------------------------------------------
// Gate+combine fused: one wave per row. x = sum(partials)+b1, exact GELU,
// logits via W2, 64-lane butterfly reduce (bit-identical on every lane ->
// every lane computes top-2; no broadcast needed), top-2 softmax, dense w,
// then fused[b,:] = wa*zs[e1,b,:] + wb*zs[e2,b,:] in the same wave.
// ---------------------------------------------------------------------------
__device__ __forceinline__ float gelu_exact(float x) {
    return 0.5f * x * (1.0f + erff(x * 0.70710678118654752f));
}

__global__ __launch_bounds__(256)
void gate_combine_kernel(const float* __restrict__ part, const float* __restrict__ b1,
                         const float* __restrict__ W2, const float* __restrict__ b2,
                         const float* __restrict__ zs, float* __restrict__ fused,
                         float* __restrict__ w_out)
{
    const int t    = threadIdx.x;
    const int wv   = t >> 6;
    const int lane = t & 63;
    const int row  = blockIdx.x * 4 + wv;

    const float* pr = part + (size_t)row * H_ + lane * 4;
    const float4 x0 = *(const float4*)pr;
    const float4 x1 = *(const float4*)(pr + (size_t)B_ * H_);
    const float4 x2 = *(const float4*)(pr + (size_t)2 * B_ * H_);
    const float4 x3 = *(const float4*)(pr + (size_t)3 * B_ * H_);
    const float4 bb = *(const float4*)&b1[lane * 4];
    const float h0 = gelu_exact(x0.x + x1.x + x2.x + x3.x + bb.x);
    const float h1 = gelu_exact(x0.y + x1.y + x2.y + x3.y + bb.y);
    const float h2 = gelu_exact(x0.z + x1.z + x2.z + x3.z + bb.z);
    const float h3 = gelu_exact(x0.w + x1.w + x2.w + x3.w + bb.w);

    float lg[8] = {0, 0, 0, 0, 0, 0, 0, 0};
    const int cb = lane * 4;
#define ACC8(HC, CI) {                                                         \
    const float4 wa_ = *(const float4*)&W2[(cb + (CI)) * 8];                   \
    const float4 wb_ = *(const float4*)&W2[(cb + (CI)) * 8 + 4];               \
    lg[0] = fmaf((HC), wa_.x, lg[0]); lg[1] = fmaf((HC), wa_.y, lg[1]);        \
    lg[2] = fmaf((HC), wa_.z, lg[2]); lg[3] = fmaf((HC), wa_.w, lg[3]);        \
    lg[4] = fmaf((HC), wb_.x, lg[4]); lg[5] = fmaf((HC), wb_.y, lg[5]);        \
    lg[6] = fmaf((HC), wb_.z, lg[6]); lg[7] = fmaf((HC), wb_.w, lg[7]);        \
}
    ACC8(h0, 0) ACC8(h1, 1) ACC8(h2, 2) ACC8(h3, 3)
#undef ACC8

#pragma unroll
    for (int off = 32; off >= 1; off >>= 1) {
#pragma unroll
        for (int i = 0; i < 8; ++i) lg[i] += __shfl_xor(lg[i], off, 64);
    }

    // Butterfly leaves bit-identical totals in every lane (operand-swapped
    // adds are commutative) -> all lanes compute the same top-2.
    float l[8];
#pragma unroll
    for (int i = 0; i < 8; ++i) l[i] = lg[i] + b2[i];
    int i1 = 0; float l1 = l[0];
#pragma unroll
    for (int i = 1; i < 8; ++i) if (l[i] > l1) { l1 = l[i]; i1 = i; }
    int i2 = (i1 == 0) ? 1 : 0; float l2 = l[i2];
#pragma unroll
    for (int i = 0; i < 8; ++i)
        if (i != i1 && l[i] > l2) { l2 = l[i]; i2 = i; }

    const float e  = expf(l2 - l1);
    const float dn = 1.0f + e;
    const float wa = 1.0f / dn;
    const float wb = e / dn;

    if (lane == 0) {
        float* wr = w_out + (size_t)row * M_;
#pragma unroll
        for (int i = 0; i < 8; ++i)
            wr[i] = (i == i1) ? wa : ((i == i2) ? wb : 0.0f);
    }

    // Combine: 1024 floats / row = 4 float4 per lane.
    const float4* z1 = (const float4*)(zs + ((size_t)i1 * B_ + row) * D_);
    const float4* z2 = (const float4*)(zs + ((size_t)i2 * B_ + row) * D_);
    float4* o = (float4*)(fused + (size_t)row * D_);
#pragma unroll
    for (int i = 0; i < 4; ++i) {
        const int d = lane + i * 64;
        const float4 x = z1[d];
        const float4 y = z2[d];
        o[d] = make_float4(fmaf(wa, x.x, wb * y.x),
                           fmaf(wa, x.y, wb * y.y),
                           fmaf(wa, x.z, wb * y.z),
                           fmaf(wa, x.w, wb * y.w));
    }
}

// ---------------------------------------------------------------------------
extern "C" void kernel_launch(void* const* d_in, const int* in_sizes, int n_in,
                              void* d_out, int out_size, void* d_ws, size_t ws_size,
                              hipStream_t stream)
{
    const float* zs = (const float*)d_in[0];
    const float* W1 = (const float*)d_in[1];
    const float* b1 = (const float*)d_in[2];
    const float* W2 = (const float*)d_in[3];
    const float* b2 = (const float*)d_in[4];

    float* fused = (float*)d_out;                    // [8192][1024]
    float* w_out = fused + (size_t)B_ * D_;          // [8192][8]

    // ws: part [4][8192][256] fp32 (32 MB) | Ph/Pm/Pl packed bf16 W1 (3 x 4 MB)
    float* part = (float*)d_ws;
    short* Ph = (short*)(part + (size_t)SPLITK * B_ * H_);
    const size_t PSZ = (size_t)NG * 2 * 256 * 8;     // shorts per component
    short* Pm = Ph + PSZ;
    short* Pl = Pm + PSZ;

    splitw1_kernel<<<NG, 256, 0, stream>>>(W1, Ph, Pm, Pl);
    gemm1_kernel<<<dim3(B_ / BM, SPLITK), 256, 0, stream>>>(zs, Ph, Pm, Pl, part);
    gate_combine_kernel<<<dim3(B_ / 4), 256, 0, stream>>>(part, b1, W2, b2, zs, fused, w_out);
}

// Round 4
// 505.680 us; speedup vs baseline: 1.0786x; 1.0455x over previous
//
#include <hip/hip_runtime.h>
#include <math.h>

// Problem constants
constexpr int B_ = 8192;   // batch rows
constexpr int D_ = 1024;   // per-expert dim
constexpr int M_ = 8;      // experts
constexpr int H_ = 256;    // gate hidden

// GEMM1: cat[8192 x 8192] @ W1[8192 x 256], fp32 via bf16-triple MFMA emulation
constexpr int SPLITK = 4;
constexpr int KSP = 2048;          // K per split (16-chunks never straddle expert boundary)
constexpr int BM = 64, BK = 16;
constexpr int NCH = KSP / BK;      // 128 chunks per block
constexpr int NG  = (M_ * D_) / BK; // 512 global 16-k chunks

typedef __bf16 bf16x8 __attribute__((ext_vector_type(8)));
typedef float  f32x16 __attribute__((ext_vector_type(16)));
typedef short  short8 __attribute__((ext_vector_type(8)));
typedef short  short2v __attribute__((ext_vector_type(2)));

__device__ __forceinline__ unsigned short f2bf(float x) {
    unsigned int u = __float_as_uint(x);
    u += 0x7FFFu + ((u >> 16) & 1u);           // round-to-nearest-even
    return (unsigned short)(u >> 16);
}
__device__ __forceinline__ float bf2f(unsigned short s) {
    return __uint_as_float(((unsigned int)s) << 16);
}

#define MFMA(A, Bf, C) __builtin_amdgcn_mfma_f32_32x32x16_bf16((A), (Bf), (C), 0, 0, 0)

// ---------------------------------------------------------------------------
// splitw1: precompute W1's h/m/l bf16 decomposition ONCE, packed per-chunk:
// P[g][ks][n][8] (g = 16-k chunk, ks = k-half, n = column). gemm1 waves then
// load their private B fragments STRAIGHT to registers (B is never shared
// across waves -- LDS round-trip for B was pure overhead).
// ---------------------------------------------------------------------------
__global__ __launch_bounds__(256)
void splitw1_kernel(const float* __restrict__ W1, short* __restrict__ Ph,
                    short* __restrict__ Pm, short* __restrict__ Pl)
{
    const int g = blockIdx.x;          // 16-k chunk
    const int t = threadIdx.x;         // column n
    float v[16];
#pragma unroll
    for (int k = 0; k < 16; ++k) v[k] = W1[(size_t)(g * 16 + k) * H_ + t];
#pragma unroll
    for (int ks = 0; ks < 2; ++ks) {
        short8 vh, vm, vl;
#pragma unroll
        for (int j = 0; j < 8; ++j) {
            const float x = v[ks * 8 + j];
            const unsigned short h = f2bf(x);
            float r = x - bf2f(h);
            const unsigned short m = f2bf(r);
            r = r - bf2f(m);
            const unsigned short l = f2bf(r);
            vh[j] = (short)h; vm[j] = (short)m; vl[j] = (short)l;
        }
        const size_t o = ((size_t)(g * 2 + ks) * 256 + t) * 8;
        *(short8*)&Ph[o] = vh;
        *(short8*)&Pm[o] = vm;
        *(short8*)&Pl[o] = vl;
    }
}

// ---------------------------------------------------------------------------
// GEMM1 v3: 512 threads (8 waves x 32-col strips), BM=64, grid 128x4 = 512
// blocks = 2 blocks/CU = 4 waves/SIMD. Only A goes through LDS (12 KB,
// double-buffered; A is broadcast to all waves). B is loaded global->reg,
// register-double-buffered across the barrier. One barrier per chunk.
// fp32 emulated as 6 bf16 passes (hh, hm, mh, mm, hl, lh) -- bit-identical.
// ---------------------------------------------------------------------------
__global__ __launch_bounds__(512, 4)
void gemm1_kernel(const float* __restrict__ zs,
                  const short* __restrict__ Ph,
                  const short* __restrict__ Pm,
                  const short* __restrict__ Pl,
                  float* __restrict__ part)
{
    // A chunk(ks,m): idx = ks*64 + m, 8 bf16 (k = ks*8..+7) for row m. 2 KB/buf.
    __shared__ short Ah[2][1024], Am_[2][1024], Al[2][1024];   // 12 KB total

    const int t  = threadIdx.x;
    const int bb0 = blockIdx.x * BM;
    const int g0 = blockIdx.y * NCH;   // global chunk base for this split

    // A staging: thread t -> row ar = t>>3 (0..63), k-octant ap = t&7 (2 floats).
    const int ar  = t >> 3;
    const int ap  = t & 7;
    const int aof = ((ap >> 2) * 64 + ar) * 8 + (ap & 3) * 2;  // short offset

    const int lane = t & 63;
    const int wv   = t >> 6;        // wave 0..7 -> cols wv*32..+31
    const int kl   = lane >> 5;     // k-half 0/1
    const int ln   = lane & 31;

    f32x16 acc0 = (f32x16)0.0f;     // rows 0..31 of tile
    f32x16 acc1 = (f32x16)0.0f;     // rows 32..63

    // B short-offset for this lane's fragment: P[g][kl][wv*32+ln][8]
    unsigned ob = ((unsigned)(g0 * 2 + kl) * 256u + (unsigned)(wv * 32 + ln)) * 8u;
    const int ia = (kl * 64 + ln) * 8;

    float2 areg;

#define LOAD_A(G) {                                                            \
    const int kg = (G) * 16;                                                   \
    areg = *(const float2*)(zs + ((size_t)(kg >> 10) * B_ + bb0 + ar) * D_     \
                               + (kg & 1023) + ap * 2);                        \
}

#define STORE_A(BUF) {                                                         \
    short2v vh, vm, vl;                                                        \
    {                                                                          \
        const float x = areg.x;                                                \
        const unsigned short h = f2bf(x); float r = x - bf2f(h);               \
        const unsigned short m = f2bf(r); r = r - bf2f(m);                     \
        const unsigned short l = f2bf(r);                                      \
        vh[0] = (short)h; vm[0] = (short)m; vl[0] = (short)l;                  \
    }                                                                          \
    {                                                                          \
        const float x = areg.y;                                                \
        const unsigned short h = f2bf(x); float r = x - bf2f(h);               \
        const unsigned short m = f2bf(r); r = r - bf2f(m);                     \
        const unsigned short l = f2bf(r);                                      \
        vh[1] = (short)h; vm[1] = (short)m; vl[1] = (short)l;                  \
    }                                                                          \
    *(short2v*)&Ah[BUF][aof]  = vh;                                            \
    *(short2v*)&Am_[BUF][aof] = vm;                                            \
    *(short2v*)&Al[BUF][aof]  = vl;                                            \
}

#define LOAD_B(DH, DM, DL, OFF) {                                              \
    DH = *(const short8*)&Ph[OFF];                                             \
    DM = *(const short8*)&Pm[OFF];                                             \
    DL = *(const short8*)&Pl[OFF];                                             \
}

    // Per-acc chain order preserved exactly: hh, hm, mh, mm, hl, lh.
#define COMPUTE(BUF, RH, RM, RL) {                                             \
    const bf16x8 vbh = __builtin_bit_cast(bf16x8, RH);                         \
    const bf16x8 vbm = __builtin_bit_cast(bf16x8, RM);                         \
    const bf16x8 vbl = __builtin_bit_cast(bf16x8, RL);                         \
    const bf16x8 ah0 = __builtin_bit_cast(bf16x8, *(const short8*)&Ah[BUF][ia]);        \
    const bf16x8 am0 = __builtin_bit_cast(bf16x8, *(const short8*)&Am_[BUF][ia]);       \
    const bf16x8 al0 = __builtin_bit_cast(bf16x8, *(const short8*)&Al[BUF][ia]);        \
    const bf16x8 ah1 = __builtin_bit_cast(bf16x8, *(const short8*)&Ah[BUF][ia + 256]);  \
    const bf16x8 am1 = __builtin_bit_cast(bf16x8, *(const short8*)&Am_[BUF][ia + 256]); \
    const bf16x8 al1 = __builtin_bit_cast(bf16x8, *(const short8*)&Al[BUF][ia + 256]);  \
    acc0 = MFMA(ah0, vbh, acc0); acc1 = MFMA(ah1, vbh, acc1);                  \
    acc0 = MFMA(ah0, vbm, acc0); acc1 = MFMA(ah1, vbm, acc1);                  \
    acc0 = MFMA(am0, vbh, acc0); acc1 = MFMA(am1, vbh, acc1);                  \
    acc0 = MFMA(am0, vbm, acc0); acc1 = MFMA(am1, vbm, acc1);                  \
    acc0 = MFMA(ah0, vbl, acc0); acc1 = MFMA(ah1, vbl, acc1);                  \
    acc0 = MFMA(al0, vbh, acc0); acc1 = MFMA(al1, vbh, acc1);                  \
}

    short8 sAh, sAm, sAl, sBh, sBm, sBl;   // register-double-buffered B frags

    // Prologue: B(chunk 0) -> regs, A(chunk 0) -> LDS buf 0.
    LOAD_B(sAh, sAm, sAl, ob)
    LOAD_A(g0)
    STORE_A(0)
    __syncthreads();

#pragma unroll 1
    for (int c = 0; c < NCH; c += 2) {
        // --- chunk c: compute from LDS buf 0 with B regs sA*.
        ob += 4096;                       // next chunk's B image (+8 KB)
        LOAD_B(sBh, sBm, sBl, ob)         // prefetch B(c+1) -> regs
        LOAD_A(g0 + c + 1)                // prefetch A(c+1) -> reg
        COMPUTE(0, sAh, sAm, sAl)
        STORE_A(1)                        // split + ds_write A(c+1) -> buf 1
        __syncthreads();                  // prefetched B survives in regs

        // --- chunk c+1: compute from LDS buf 1 with B regs sB*.
        if (c + 2 < NCH) {
            ob += 4096;
            LOAD_B(sAh, sAm, sAl, ob)     // prefetch B(c+2)
            LOAD_A(g0 + c + 2)
        }
        COMPUTE(1, sBh, sBm, sBl)
        if (c + 2 < NCH) STORE_A(0)
        __syncthreads();
    }
#undef LOAD_A
#undef STORE_A
#undef LOAD_B
#undef COMPUTE

    // Epilogue: C/D layout (verified m74/m101): col = ln, row = (r&3)+8*(r>>2)+4*kl
    float* P = part + ((size_t)blockIdx.y * B_ + bb0) * H_;
    const int col = wv * 32 + ln;
#pragma unroll
    for (int r = 0; r < 16; ++r) {
        const int row0 = (r & 3) + 8 * (r >> 2) + 4 * kl;
        P[(size_t)row0 * H_ + col]        = acc0[r];
        P[(size_t)(row0 + 32) * H_ + col] = acc1[r];
    }
}

// ---------------------------------------------------------------------------
// Gate+combine fused: one wave per row. x = sum(partials)+b1, exact GELU,
// logits via W2, 64-lane butterfly reduce (bit-identical on every lane ->
// every lane computes top-2; no broadcast needed), top-2 softmax, dense w,
// then fused[b,:] = wa*zs[e1,b,:] + wb*zs[e2,b,:] in the same wave.
// ---------------------------------------------------------------------------
__device__ __forceinline__ float gelu_exact(float x) {
    return 0.5f * x * (1.0f + erff(x * 0.70710678118654752f));
}

__global__ __launch_bounds__(256)
void gate_combine_kernel(const float* __restrict__ part, const float* __restrict__ b1,
                         const float* __restrict__ W2, const float* __restrict__ b2,
                         const float* __restrict__ zs, float* __restrict__ fused,
                         float* __restrict__ w_out)
{
    const int t    = threadIdx.x;
    const int wv   = t >> 6;
    const int lane = t & 63;
    const int row  = blockIdx.x * 4 + wv;

    const float* pr = part + (size_t)row * H_ + lane * 4;
    const float4 x0 = *(const float4*)pr;
    const float4 x1 = *(const float4*)(pr + (size_t)B_ * H_);
    const float4 x2 = *(const float4*)(pr + (size_t)2 * B_ * H_);
    const float4 x3 = *(const float4*)(pr + (size_t)3 * B_ * H_);
    const float4 bb = *(const float4*)&b1[lane * 4];
    const float h0 = gelu_exact(x0.x + x1.x + x2.x + x3.x + bb.x);
    const float h1 = gelu_exact(x0.y + x1.y + x2.y + x3.y + bb.y);
    const float h2 = gelu_exact(x0.z + x1.z + x2.z + x3.z + bb.z);
    const float h3 = gelu_exact(x0.w + x1.w + x2.w + x3.w + bb.w);

    float lg[8] = {0, 0, 0, 0, 0, 0, 0, 0};
    const int cb = lane * 4;
#define ACC8(HC, CI) {                                                         \
    const float4 wa_ = *(const float4*)&W2[(cb + (CI)) * 8];                   \
    const float4 wb_ = *(const float4*)&W2[(cb + (CI)) * 8 + 4];               \
    lg[0] = fmaf((HC), wa_.x, lg[0]); lg[1] = fmaf((HC), wa_.y, lg[1]);        \
    lg[2] = fmaf((HC), wa_.z, lg[2]); lg[3] = fmaf((HC), wa_.w, lg[3]);        \
    lg[4] = fmaf((HC), wb_.x, lg[4]); lg[5] = fmaf((HC), wb_.y, lg[5]);        \
    lg[6] = fmaf((HC), wb_.z, lg[6]); lg[7] = fmaf((HC), wb_.w, lg[7]);        \
}
    ACC8(h0, 0) ACC8(h1, 1) ACC8(h2, 2) ACC8(h3, 3)
#undef ACC8

#pragma unroll
    for (int off = 32; off >= 1; off >>= 1) {
#pragma unroll
        for (int i = 0; i < 8; ++i) lg[i] += __shfl_xor(lg[i], off, 64);
    }

    // Butterfly leaves bit-identical totals in every lane -> all lanes
    // compute the same top-2.
    float l[8];
#pragma unroll
    for (int i = 0; i < 8; ++i) l[i] = lg[i] + b2[i];
    int i1 = 0; float l1 = l[0];
#pragma unroll
    for (int i = 1; i < 8; ++i) if (l[i] > l1) { l1 = l[i]; i1 = i; }
    int i2 = (i1 == 0) ? 1 : 0; float l2 = l[i2];
#pragma unroll
    for (int i = 0; i < 8; ++i)
        if (i != i1 && l[i] > l2) { l2 = l[i]; i2 = i; }

    const float e  = expf(l2 - l1);
    const float dn = 1.0f + e;
    const float wa = 1.0f / dn;
    const float wb = e / dn;

    if (lane == 0) {
        float* wr = w_out + (size_t)row * M_;
#pragma unroll
        for (int i = 0; i < 8; ++i)
            wr[i] = (i == i1) ? wa : ((i == i2) ? wb : 0.0f);
    }

    // Combine: 1024 floats / row = 4 float4 per lane.
    const float4* z1 = (const float4*)(zs + ((size_t)i1 * B_ + row) * D_);
    const float4* z2 = (const float4*)(zs + ((size_t)i2 * B_ + row) * D_);
    float4* o = (float4*)(fused + (size_t)row * D_);
#pragma unroll
    for (int i = 0; i < 4; ++i) {
        const int d = lane + i * 64;
        const float4 x = z1[d];
        const float4 y = z2[d];
        o[d] = make_float4(fmaf(wa, x.x, wb * y.x),
                           fmaf(wa, x.y, wb * y.y),
                           fmaf(wa, x.z, wb * y.z),
                           fmaf(wa, x.w, wb * y.w));
    }
}

// ---------------------------------------------------------------------------
extern "C" void kernel_launch(void* const* d_in, const int* in_sizes, int n_in,
                              void* d_out, int out_size, void* d_ws, size_t ws_size,
                              hipStream_t stream)
{
    const float* zs = (const float*)d_in[0];
    const float* W1 = (const float*)d_in[1];
    const float* b1 = (const float*)d_in[2];
    const float* W2 = (const float*)d_in[3];
    const float* b2 = (const float*)d_in[4];

    float* fused = (float*)d_out;                    // [8192][1024]
    float* w_out = fused + (size_t)B_ * D_;          // [8192][8]

    // ws: part [4][8192][256] fp32 (32 MB) | Ph/Pm/Pl packed bf16 W1 (3 x 4 MB)
    float* part = (float*)d_ws;
    short* Ph = (short*)(part + (size_t)SPLITK * B_ * H_);
    const size_t PSZ = (size_t)NG * 2 * 256 * 8;     // shorts per component
    short* Pm = Ph + PSZ;
    short* Pl = Pm + PSZ;

    splitw1_kernel<<<NG, 256, 0, stream>>>(W1, Ph, Pm, Pl);
    gemm1_kernel<<<dim3(B_ / BM, SPLITK), 512, 0, stream>>>(zs, Ph, Pm, Pl, part);
    gate_combine_kernel<<<dim3(B_ / 4), 256, 0, stream>>>(part, b1, W2, b2, zs, fused, w_out);
}